// Round 4
// baseline (60.498 us; speedup 1.0000x reference)
//
#include <hip/hip_runtime.h>
#include <cstdint>

namespace {

constexpr int NB = 320;   // batch
constexpr int ND = 128;   // feature dim
constexpr int NC = 80;    // label dim
constexpr int NANCH = 30;
constexpr int NW = 5;     // 64-bit words per 320-bit row

// ---- workspace layout (byte offsets) ----
constexpr size_t OFF_FD   = 0;          // float[320*320] = 409600 B
constexpr size_t OFF_PACK = 409600;     // u64[640]
constexpr size_t OFF_CNT  = 414720;     // float[320] label popcount
constexpr size_t OFF_DIV  = 416000;     // float[320]

// K1: per-row prep (src norm, label pack) + fd row + diversity mean.
// NOTE: bit-exact vs reference (absmax 0.0) -- do not alter reduction order.
__global__ __launch_bounds__(256) void k_fd(
    const int* __restrict__ label,
    const float* __restrict__ src,
    const float* __restrict__ tgt,
    float* __restrict__ fd,
    unsigned long long* __restrict__ packed,
    float* __restrict__ cnt,
    float* __restrict__ divr)
{
    const int a = blockIdx.x;
    const int tid = threadIdx.x;
    const int w = tid >> 6, lane = tid & 63;

    __shared__ float sa[ND];
    __shared__ float snsa;
    __shared__ float red[256];

    if (tid < ND) sa[tid] = src[a * ND + tid];
    if (w == 0) {
        float s0 = src[a * ND + lane];
        float s1 = src[a * ND + lane + 64];
        float v = s0 * s0 + s1 * s1;
        for (int off = 32; off > 0; off >>= 1) v += __shfl_down(v, off);
        if (lane == 0) snsa = sqrtf(v);
    } else if (w == 1) {
        int l0 = label[a * NC + lane];                              // c 0..63
        int l1 = (lane < NC - 64) ? label[a * NC + 64 + lane] : 0;  // c 64..79
        unsigned long long b0 = __ballot(l0 != 0);
        unsigned long long b1 = __ballot(l1 != 0);
        if (lane == 0) {
            packed[2 * a] = b0;
            packed[2 * a + 1] = b1;
            cnt[a] = (float)(__popcll(b0) + __popcll(b1));
        }
    }
    __syncthreads();

    const float nsa = snsa;
    float acc = 0.f;
    for (int j = tid; j < NB; j += 256) {
        const float4* tp = reinterpret_cast<const float4*>(tgt + j * ND);
        float dot = 0.f, tn = 0.f;
#pragma unroll
        for (int d = 0; d < ND / 4; ++d) {
            float4 t = tp[d];
            dot += sa[4 * d + 0] * t.x + sa[4 * d + 1] * t.y +
                   sa[4 * d + 2] * t.z + sa[4 * d + 3] * t.w;
            tn += t.x * t.x + t.y * t.y + t.z * t.z + t.w * t.w;
        }
        float sim = dot / fmaxf(nsa * sqrtf(tn), 1e-8f);
        float f = fmaxf(1.0f - sim, 0.0f);
        fd[a * NB + j] = f;
        acc += f;
    }
    red[tid] = acc;
    __syncthreads();
    for (int st = 128; st > 0; st >>= 1) {
        if (tid < st) red[tid] += red[tid + st];
        __syncthreads();
    }
    if (tid == 0) divr[a] = red[0] / (float)NB;
}

// K2: single block, fully parallel tail. No serial selection rounds, no
// ballots, no atomics -- all stages are throughput-parallel and deterministic.
__global__ __launch_bounds__(256) void k_tail(
    const unsigned long long* __restrict__ packed,
    const float* __restrict__ cnt,
    const float* __restrict__ fd,
    const float* __restrict__ divr,
    float* __restrict__ out)
{
    const int tid = threadIdx.x;

    __shared__ float dv[NB];
    __shared__ float snl[NB];
    __shared__ unsigned long long pk[2 * NB];
    __shared__ int alist[NANCH];
    __shared__ float fdr[NANCH][NB];                    // 38400 B
    __shared__ unsigned long long pmask[NANCH][NW], nmask[NANCH][NW];
    __shared__ double sred[256];
    __shared__ int pcnt[NANCH], ncnt[NANCH];
    __shared__ long long totcnt;

    for (int j = tid; j < NB; j += 256) {
        dv[j] = divr[j];
        snl[j] = sqrtf(cnt[j]);
    }
    for (int j = tid; j < 2 * NB; j += 256) pk[j] = packed[j];
    __syncthreads();

    // ---- top-30 via parallel rank (ties -> lowest index, = lax.top_k) ----
    for (int e = tid; e < NB; e += 256) {
        const float ve = dv[e];
        int rank = 0;
#pragma unroll 8
        for (int j = 0; j < NB; ++j) {
            float vj = dv[j];
            rank += (vj > ve) || (vj == ve && j < e);
        }
        if (rank < NANCH) alist[rank] = e;   // ranks unique -> no collision
    }
    __syncthreads();

    // ---- prefetch all 30 anchor fd rows into LDS (parallel float4) ----
    for (int u = tid; u < NANCH * (NB / 4); u += 256) {
        int r = u / (NB / 4);
        int q = u - r * (NB / 4);
        reinterpret_cast<float4*>(fdr[r])[q] =
            reinterpret_cast<const float4*>(fd + (size_t)alist[r] * NB)[q];
    }

    // ---- classification: thread owns (word wd, anchor r); r fastest so
    //      pk reads broadcast within a wave. Deterministic, atomic-free. ----
    if (tid < NW * NANCH) {
        const int wd = tid / NANCH, r = tid - wd * NANCH;
        const int a2 = alist[r];
        const unsigned long long a0 = pk[2 * a2], a1 = pk[2 * a2 + 1];
        const float sna = snl[a2];
        unsigned long long pm = 0, nm = 0;
        for (int b = 0; b < 64; ++b) {
            const int j = wd * 64 + b;
            if (j == a2) continue;
            const float denom = sna * snl[j];
            if (!(denom > 0.f)) continue;    // zero-label row -> NaN in ref -> excluded
            float dotf = (float)(__popcll(a0 & pk[2 * j]) + __popcll(a1 & pk[2 * j + 1]));
            float ld = 1.0f - fminf(1.0f, dotf / denom);
            if (ld <= 0.2f)      pm |= 1ull << b;
            else if (ld >= 0.5f) nm |= 1ull << b;   // disjoint -> p != n automatic
        }
        pmask[r][wd] = pm;
        nmask[r][wd] = nm;
    }
    __syncthreads();

    if (tid < NANCH) {
        int p = 0, n = 0;
#pragma unroll
        for (int wd = 0; wd < NW; ++wd) {
            p += __popcll(pmask[tid][wd]);
            n += __popcll(nmask[tid][wd]);
        }
        pcnt[tid] = p;
        ncnt[tid] = n;
    }
    __syncthreads();
    if (tid == 0) {
        long long c = 0;
        for (int r = 0; r < NANCH; ++r) c += (long long)pcnt[r] * ncnt[r];
        totcnt = c;
    }

    // ---- triplet sum: parallel over (anchor, n); tiny ctz loop over pos ----
    double s = 0.0;
    for (int u = tid; u < NANCH * NB; u += 256) {
        const int r = u / NB, j = u - r * NB;
        if ((nmask[r][j >> 6] >> (j & 63)) & 1ull) {
            const float fn = fdr[r][j];
#pragma unroll
            for (int wd = 0; wd < NW; ++wd) {
                unsigned long long m = pmask[r][wd];
                while (m) {
                    const int b = __builtin_ctzll(m);
                    m &= m - 1;
                    float v = fdr[r][wd * 64 + b] - fn + 0.5f;
                    if (v > 0.f) s += (double)v;
                }
            }
        }
    }
    sred[tid] = s;
    __syncthreads();
    for (int st = 128; st > 0; st >>= 1) {
        if (tid < st) sred[tid] += sred[tid + st];
        __syncthreads();
    }
    if (tid == 0) out[0] = (float)(sred[0] / ((double)totcnt + 1e-4));
}

} // namespace

extern "C" void kernel_launch(void* const* d_in, const int* in_sizes, int n_in,
                              void* d_out, int out_size, void* d_ws, size_t ws_size,
                              hipStream_t stream) {
    const int* label = (const int*)d_in[0];
    const float* src = (const float*)d_in[1];
    const float* tgt = (const float*)d_in[2];

    char* ws = (char*)d_ws;
    float* fd = (float*)(ws + OFF_FD);
    unsigned long long* packed = (unsigned long long*)(ws + OFF_PACK);
    float* cnt = (float*)(ws + OFF_CNT);
    float* divr = (float*)(ws + OFF_DIV);

    k_fd  <<<NB, 256, 0, stream>>>(label, src, tgt, fd, packed, cnt, divr);
    k_tail<<<1, 256, 0, stream>>>(packed, cnt, fd, divr, (float*)d_out);
}

// Round 5
// 35.354 us; speedup vs baseline: 1.7112x; 1.7112x over previous
//
#include <hip/hip_runtime.h>
#include <cstdint>

namespace {

constexpr int NB = 320;   // batch
constexpr int ND = 128;   // feature dim
constexpr int NC = 80;    // label dim
constexpr int NANCH = 30;
constexpr int NW = 5;     // 64-bit words per 320-bit row

// ---- workspace layout (byte offsets) ----
constexpr size_t OFF_FD   = 0;          // float[320*320]
constexpr size_t OFF_PACK = 409600;     // u64[640]
constexpr size_t OFF_CNT  = 414720;     // float[320]
constexpr size_t OFF_DIV  = 416000;     // float[320]

// K1: per-row prep (src norm, label pack) + fd row + diversity mean.
// Bit-exact vs reference (absmax 0.0) -- do not alter reduction order.
__global__ __launch_bounds__(256) void k_fd(
    const int* __restrict__ label,
    const float* __restrict__ src,
    const float* __restrict__ tgt,
    float* __restrict__ fd,
    unsigned long long* __restrict__ packed,
    float* __restrict__ cnt,
    float* __restrict__ divr)
{
    const int a = blockIdx.x;
    const int tid = threadIdx.x;
    const int w = tid >> 6, lane = tid & 63;

    __shared__ float sa[ND];
    __shared__ float snsa;
    __shared__ float red[256];

    if (tid < ND) sa[tid] = src[a * ND + tid];
    if (w == 0) {
        float s0 = src[a * ND + lane];
        float s1 = src[a * ND + lane + 64];
        float v = s0 * s0 + s1 * s1;
        for (int off = 32; off > 0; off >>= 1) v += __shfl_down(v, off);
        if (lane == 0) snsa = sqrtf(v);
    } else if (w == 1) {
        int l0 = label[a * NC + lane];
        int l1 = (lane < NC - 64) ? label[a * NC + 64 + lane] : 0;
        unsigned long long b0 = __ballot(l0 != 0);
        unsigned long long b1 = __ballot(l1 != 0);
        if (lane == 0) {
            packed[2 * a] = b0;
            packed[2 * a + 1] = b1;
            cnt[a] = (float)(__popcll(b0) + __popcll(b1));
        }
    }
    __syncthreads();

    const float nsa = snsa;
    float acc = 0.f;
    for (int j = tid; j < NB; j += 256) {
        const float4* tp = reinterpret_cast<const float4*>(tgt + j * ND);
        float dot = 0.f, tn = 0.f;
#pragma unroll
        for (int d = 0; d < ND / 4; ++d) {
            float4 t = tp[d];
            dot += sa[4 * d + 0] * t.x + sa[4 * d + 1] * t.y +
                   sa[4 * d + 2] * t.z + sa[4 * d + 3] * t.w;
            tn += t.x * t.x + t.y * t.y + t.z * t.z + t.w * t.w;
        }
        float sim = dot / fmaxf(nsa * sqrtf(tn), 1e-8f);
        float f = fmaxf(1.0f - sim, 0.0f);
        fd[a * NB + j] = f;
        acc += f;
    }
    red[tid] = acc;
    __syncthreads();
    for (int st = 128; st > 0; st >>= 1) {
        if (tid < st) red[tid] += red[tid + st];
        __syncthreads();
    }
    if (tid == 0) divr[a] = red[0] / (float)NB;
}

// K2: single 16-wave block. Every phase 64-wide per wave; classification is
// one ballot per mask word (320 = 5*64 -> each wave owns exactly one word).
__global__ __launch_bounds__(1024) void k_tail(
    const unsigned long long* __restrict__ packed,
    const float* __restrict__ cnt,
    const float* __restrict__ fd,
    const float* __restrict__ divr,
    float* __restrict__ out)
{
    const int tid = threadIdx.x;
    const int lane = tid & 63;
    const int wv = tid >> 6;                 // 0..15

    __shared__ float dv[NB], snl[NB];
    __shared__ unsigned long long pk[2 * NB];
    __shared__ int alist[NANCH];
    __shared__ float fdr[NANCH][NB];         // 38400 B
    __shared__ unsigned long long pmask[NANCH][NW], nmask[NANCH][NW];
    __shared__ int prod[NANCH];
    __shared__ int totcnt;
    __shared__ double wsum[16];

    if (tid < NB) { dv[tid] = divr[tid]; snl[tid] = sqrtf(cnt[tid]); }
    if (tid < 2 * NB) pk[tid] = packed[tid];
    __syncthreads();

    // ---- top-30 via parallel rank (ties -> lowest index, = lax.top_k) ----
    if (tid < NB) {
        const float ve = dv[tid];
        int rank = 0;
#pragma unroll 8
        for (int j = 0; j < NB; ++j) {
            float vj = dv[j];
            rank += (vj > ve) || (vj == ve && j < tid);
        }
        if (rank < NANCH) alist[rank] = tid;  // ranks unique -> no collision
    }
    __syncthreads();

    // ---- prefetch all 30 anchor fd rows into LDS (independent float4) ----
    for (int u = tid; u < NANCH * (NB / 4); u += 1024) {
        int r = u / (NB / 4);
        int q = u - r * (NB / 4);
        reinterpret_cast<float4*>(fdr[r])[q] =
            reinterpret_cast<const float4*>(fd + (size_t)alist[r] * NB)[q];
    }

    // ---- classification: wave-per-word, one ballot per (r, word) ----
    for (int it = 0; it < 10; ++it) {
        const int u = tid + 1024 * it;       // wave-uniform guard: 320 % 64 == 0
        if (u < NANCH * NB) {
            const int r = u / NB;
            const int j = u - r * NB;        // consecutive j across the wave
            const int a2 = alist[r];
            const float denom = snl[a2] * snl[j];
            const float dotf = (float)(__popcll(pk[2 * a2] & pk[2 * j]) +
                                       __popcll(pk[2 * a2 + 1] & pk[2 * j + 1]));
            const float ld = 1.0f - fminf(1.0f, dotf / denom);
            const bool valid = (j != a2) && (denom > 0.f); // zero-label -> NaN in ref -> excluded
            unsigned long long pb = __ballot(valid && (ld <= 0.2f));
            unsigned long long nb = __ballot(valid && (ld >= 0.5f));
            if (lane == 0) {                 // whole wave maps into one word
                pmask[r][j >> 6] = pb;
                nmask[r][j >> 6] = nb;
            }
        }
    }
    __syncthreads();                          // masks + fdr ready

    if (tid < NANCH) {
        int p = 0, n = 0;
#pragma unroll
        for (int wd = 0; wd < NW; ++wd) {
            p += __popcll(pmask[tid][wd]);
            n += __popcll(nmask[tid][wd]);
        }
        prod[tid] = p * n;                    // pos/neg disjoint -> p != n automatic
    }
    __syncthreads();
    if (tid == 0) {
        int c = 0;
#pragma unroll
        for (int r = 0; r < NANCH; ++r) c += prod[r];
        totcnt = c;
    }

    // ---- triplet sum: parallel over (anchor, n); short ctz loop over pos ----
    double s = 0.0;
    for (int it = 0; it < 10; ++it) {
        const int u = tid + 1024 * it;
        if (u < NANCH * NB) {
            const int r = u / NB, j = u - r * NB;
            if ((nmask[r][j >> 6] >> (j & 63)) & 1ull) {
                const float fn = fdr[r][j];
#pragma unroll
                for (int wd = 0; wd < NW; ++wd) {
                    unsigned long long m = pmask[r][wd];
                    while (m) {
                        const int b = __builtin_ctzll(m);
                        m &= m - 1;
                        float v = fdr[r][wd * 64 + b] - fn + 0.5f;
                        if (v > 0.f) s += (double)v;
                    }
                }
            }
        }
    }
    for (int off = 32; off > 0; off >>= 1) s += __shfl_down(s, off);
    if (lane == 0) wsum[wv] = s;
    __syncthreads();
    if (wv == 0) {
        double t = (lane < 16) ? wsum[lane] : 0.0;
        for (int off = 8; off > 0; off >>= 1) t += __shfl_down(t, off);
        if (lane == 0) out[0] = (float)(t / ((double)totcnt + 1e-4));
    }
}

} // namespace

extern "C" void kernel_launch(void* const* d_in, const int* in_sizes, int n_in,
                              void* d_out, int out_size, void* d_ws, size_t ws_size,
                              hipStream_t stream) {
    const int* label = (const int*)d_in[0];
    const float* src = (const float*)d_in[1];
    const float* tgt = (const float*)d_in[2];

    char* ws = (char*)d_ws;
    float* fd = (float*)(ws + OFF_FD);
    unsigned long long* packed = (unsigned long long*)(ws + OFF_PACK);
    float* cnt = (float*)(ws + OFF_CNT);
    float* divr = (float*)(ws + OFF_DIV);

    k_fd  <<<NB, 256, 0, stream>>>(label, src, tgt, fd, packed, cnt, divr);
    k_tail<<<1, 1024, 0, stream>>>(packed, cnt, fd, divr, (float*)d_out);
}